// Round 10
// baseline (103.479 us; speedup 1.0000x reference)
//
#include <hip/hip_runtime.h>

// GCN layer, transform-first pipeline:
//   k_init  : zero degree array
//   k_build : scan A once -> u16 CSR + column degrees (atomic +1.0, exact)
//   k_dinv  : dinv = rsqrt(1 + deg)
//   k_xform : y = x @ W^T in fp16 via MFMA 16x16x32 (fp32 accum), layout [b][n][o]
//   k_agg2  : out[b,n,:] = dinv[n]*(sum_m dinv[m]*y[b,m,:] + dinv[n]*y[b,n,:]) + bias
// k_agg2: R5-proven f32 fma_mix gather loop, fused over 4 batches per block:
// sL staged once per (node, 4 batches); per slot one ds_read_b64 serves 4 batch
// loads + 32 fma. f16 *storage* only — all accumulation in f32 (pk-f16 acc NaN'd
// in R6/R7; reverted). [R9 resubmit: container unresponsive twice, no data]

#define NN 4096
#define FD 128
#define NB 16
#define CAP 96      // max neighbors/row (mean ~41, sd ~6.4; 96 = +8.6 sigma)
#define CPAD 100    // (CAP+1 self) padded to multiple of 4

typedef float     f32x2 __attribute__((ext_vector_type(2)));
typedef float     f32x4 __attribute__((ext_vector_type(4)));
typedef _Float16  f16x4 __attribute__((ext_vector_type(4)));
typedef _Float16  f16x8 __attribute__((ext_vector_type(8)));
typedef int       i32x2 __attribute__((ext_vector_type(2)));

__global__ __launch_bounds__(256) void k_init(float* __restrict__ deg) {
    deg[blockIdx.x * 256 + threadIdx.x] = 0.0f;
}

__global__ __launch_bounds__(256) void k_build(const float* __restrict__ A,
                                               float* __restrict__ deg,
                                               int* __restrict__ cnt,
                                               unsigned short* __restrict__ csr) {
    __shared__ int sCnt[256];
    const int n = blockIdx.x, t = threadIdx.x;
    const float* row = A + (size_t)n * NN + t * 16;
    float r[16];
    *(f32x4*)&r[0]  = ((const f32x4*)row)[0];
    *(f32x4*)&r[4]  = ((const f32x4*)row)[1];
    *(f32x4*)&r[8]  = ((const f32x4*)row)[2];
    *(f32x4*)&r[12] = ((const f32x4*)row)[3];

    int c = 0;
    #pragma unroll
    for (int j = 0; j < 16; ++j) c += (r[j] != 0.0f) ? 1 : 0;
    sCnt[t] = c;
    __syncthreads();
    for (int off = 1; off < 256; off <<= 1) {
        const int v = sCnt[t];
        const int u = (t >= off) ? sCnt[t - off] : 0;
        __syncthreads();
        sCnt[t] = v + u;
        __syncthreads();
    }
    int pos = sCnt[t] - c;                      // exclusive prefix (sorted order)
    #pragma unroll
    for (int j = 0; j < 16; ++j) {
        if (r[j] != 0.0f) {
            const int m = t * 16 + j;
            if (pos < CAP) csr[(size_t)n * CAP + pos] = (unsigned short)m;
            ++pos;
            atomicAdd(&deg[m], 1.0f);           // exact integer-valued fp adds
        }
    }
    if (t == 255) {
        int tot = sCnt[255];
        cnt[n] = tot < CAP ? tot : CAP;
    }
}

__global__ __launch_bounds__(256) void k_dinv(const float* __restrict__ deg,
                                              float* __restrict__ dinv) {
    const int i = blockIdx.x * 256 + threadIdx.x;
    dinv[i] = rsqrtf(1.0f + deg[i]);
}

// ---- MFMA transform: y[r][o] = sum_f x[r][f] * W[o][f], fp16 out ----
#define XR 128
#define XP 136
__global__ __launch_bounds__(256) void k_xform(const float* __restrict__ x,
                                               const float* __restrict__ W,
                                               _Float16* __restrict__ y) {
    __shared__ _Float16 sX[XR][XP];   // 34.8 KB
    __shared__ _Float16 sW[FD][XP];   // 34.8 KB
    const int t = threadIdx.x;
    const size_t rbase = (size_t)blockIdx.x * XR;

    #pragma unroll
    for (int i = 0; i < 8; ++i) {
        const int id = t + i * 256;
        const int o = id >> 4, f8 = (id & 15) * 8;
        const f32x4 a = *(const f32x4*)&W[(size_t)o * FD + f8];
        const f32x4 b = *(const f32x4*)&W[(size_t)o * FD + f8 + 4];
        f16x8 h;
        h[0]=(_Float16)a.x; h[1]=(_Float16)a.y; h[2]=(_Float16)a.z; h[3]=(_Float16)a.w;
        h[4]=(_Float16)b.x; h[5]=(_Float16)b.y; h[6]=(_Float16)b.z; h[7]=(_Float16)b.w;
        *(f16x8*)&sW[o][f8] = h;
    }
    #pragma unroll
    for (int i = 0; i < 8; ++i) {
        const int id = t + i * 256;
        const int r = id >> 4, f8 = (id & 15) * 8;
        const f32x4 a = *(const f32x4*)&x[(rbase + r) * FD + f8];
        const f32x4 b = *(const f32x4*)&x[(rbase + r) * FD + f8 + 4];
        f16x8 h;
        h[0]=(_Float16)a.x; h[1]=(_Float16)a.y; h[2]=(_Float16)a.z; h[3]=(_Float16)a.w;
        h[4]=(_Float16)b.x; h[5]=(_Float16)b.y; h[6]=(_Float16)b.z; h[7]=(_Float16)b.w;
        *(f16x8*)&sX[r][f8] = h;
    }
    __syncthreads();

    const int w = t >> 6, lane = t & 63;
    const int lrow = lane & 15, koct = (lane >> 4) * 8;
    f32x4 acc[2][8] = {};
    #pragma unroll
    for (int kc = 0; kc < 4; ++kc) {
        const int ko = kc * 32 + koct;
        f16x8 aa0 = *(const f16x8*)&sX[w * 32 + lrow][ko];
        f16x8 aa1 = *(const f16x8*)&sX[w * 32 + 16 + lrow][ko];
        #pragma unroll
        for (int nt = 0; nt < 8; ++nt) {
            const f16x8 bb = *(const f16x8*)&sW[nt * 16 + lrow][ko];
            acc[0][nt] = __builtin_amdgcn_mfma_f32_16x16x32_f16(aa0, bb, acc[0][nt], 0, 0, 0);
            acc[1][nt] = __builtin_amdgcn_mfma_f32_16x16x32_f16(aa1, bb, acc[1][nt], 0, 0, 0);
        }
    }
    // C layout (m89-verified): col = lane&15, row = (lane>>4)*4 + reg
    #pragma unroll
    for (int mt = 0; mt < 2; ++mt) {
        const size_t row0 = rbase + w * 32 + mt * 16 + (lane >> 4) * 4;
        #pragma unroll
        for (int nt = 0; nt < 8; ++nt) {
            const int col = nt * 16 + (lane & 15);
            #pragma unroll
            for (int r = 0; r < 4; ++r)
                y[(row0 + r) * FD + col] = (_Float16)acc[mt][nt][r];
        }
    }
}

// ---- aggregation: grid (NN/4, NB/4), 256 thr; wave w owns node 4*bx+w and
// batches 4*by..4*by+3. lane: rq = lane>>4 (slot class), fo = (lane&15)*8.
__global__ __launch_bounds__(256) void k_agg2(const _Float16* __restrict__ y,
                                              const int* __restrict__ cnt,
                                              const unsigned short* __restrict__ csr,
                                              const float* __restrict__ dinv,
                                              const float* __restrict__ bias,
                                              float* __restrict__ out) {
    __shared__ int sL[4][CPAD * 2];              // (element-offset m*FD, f32 wt bits)
    const int t = threadIdx.x, w = t >> 6, lane = t & 63;
    const int n = blockIdx.x * 4 + w;
    const int b0 = blockIdx.y * 4;
    const int c = cnt[n];
    const int totPad = (c + 1 + 3) & ~3;         // +self, pad to x4 (zero-weight)

    for (int k = lane; k < totPad; k += 64) {
        int m; float wv;
        if (k < c)       { m = csr[(size_t)n * CAP + k]; wv = dinv[m]; }
        else if (k == c) { m = n; wv = dinv[n]; }
        else             { m = n; wv = 0.0f; }
        sL[w][2 * k]     = m << 7;               // element offset (m * FD)
        sL[w][2 * k + 1] = __float_as_int(wv);
    }
    __syncthreads();

    const int rq = lane >> 4, fo = (lane & 15) * 8;
    const _Float16* yb = y + (size_t)b0 * (NN * FD) + fo;

    float acc[4][8] = {};
    i32x2 e = *(const i32x2*)&sL[w][2 * rq];
    f16x8 p0 = *(const f16x8*)(yb + 0 * (size_t)(NN * FD) + e.x);
    f16x8 p1 = *(const f16x8*)(yb + 1 * (size_t)(NN * FD) + e.x);
    f16x8 p2 = *(const f16x8*)(yb + 2 * (size_t)(NN * FD) + e.x);
    f16x8 p3 = *(const f16x8*)(yb + 3 * (size_t)(NN * FD) + e.x);
    float wt = __int_as_float(e.y);
    for (int k = rq + 4; k < totPad; k += 4) {
        const i32x2 e2 = *(const i32x2*)&sL[w][2 * k];
        const f16x8 n0 = *(const f16x8*)(yb + 0 * (size_t)(NN * FD) + e2.x);
        const f16x8 n1 = *(const f16x8*)(yb + 1 * (size_t)(NN * FD) + e2.x);
        const f16x8 n2 = *(const f16x8*)(yb + 2 * (size_t)(NN * FD) + e2.x);
        const f16x8 n3 = *(const f16x8*)(yb + 3 * (size_t)(NN * FD) + e2.x);
        const float wt2 = __int_as_float(e2.y);
        #pragma unroll
        for (int j = 0; j < 8; ++j) {
            acc[0][j] = fmaf(wt, (float)p0[j], acc[0][j]);
            acc[1][j] = fmaf(wt, (float)p1[j], acc[1][j]);
            acc[2][j] = fmaf(wt, (float)p2[j], acc[2][j]);
            acc[3][j] = fmaf(wt, (float)p3[j], acc[3][j]);
        }
        p0 = n0; p1 = n1; p2 = n2; p3 = n3; wt = wt2;
    }
    #pragma unroll
    for (int j = 0; j < 8; ++j) {
        acc[0][j] = fmaf(wt, (float)p0[j], acc[0][j]);
        acc[1][j] = fmaf(wt, (float)p1[j], acc[1][j]);
        acc[2][j] = fmaf(wt, (float)p2[j], acc[2][j]);
        acc[3][j] = fmaf(wt, (float)p3[j], acc[3][j]);
    }

    // reduce the 4 slot-class partials across lanes (xor 16, then 32), in f32
    #pragma unroll
    for (int q = 0; q < 4; ++q)
        #pragma unroll
        for (int j = 0; j < 8; ++j) {
            acc[q][j] += __shfl_xor(acc[q][j], 16);
            acc[q][j] += __shfl_xor(acc[q][j], 32);
        }

    if (lane < 32) {
        const float dn = dinv[n];
        const int h = lane >> 4;                 // low/high quad of my octet
        const int f0 = (lane & 15) * 8 + h * 4;
        const f32x4 bb = *(const f32x4*)(bias + f0);
        #pragma unroll
        for (int q = 0; q < 4; ++q) {
            f32x4 o;
            o.x = acc[q][h * 4 + 0] * dn + bb.x;
            o.y = acc[q][h * 4 + 1] * dn + bb.y;
            o.z = acc[q][h * 4 + 2] * dn + bb.z;
            o.w = acc[q][h * 4 + 3] * dn + bb.w;
            f32x4* dst = (f32x4*)(out + ((size_t)(b0 + q) * NN + n) * FD + f0);
            __builtin_nontemporal_store(o, dst);
        }
    }
}

extern "C" void kernel_launch(void* const* d_in, const int* in_sizes, int n_in,
                              void* d_out, int out_size, void* d_ws, size_t ws_size,
                              hipStream_t stream) {
    const float* A    = (const float*)d_in[0];   // (4096,4096)
    const float* x    = (const float*)d_in[1];   // (16,4096,128)
    const float* W    = (const float*)d_in[2];   // (128,128)
    const float* bias = (const float*)d_in[3];   // (128,)
    float* out = (float*)d_out;                  // (16,4096,128)

    // ws layout: deg 16K | dinv 16K | cnt 16K | csr 768K | y fp16 16M  (~17 MB)
    float*          deg  = (float*)d_ws;
    float*          dinv = deg + NN;
    int*            cnt  = (int*)(dinv + NN);
    unsigned short* csr  = (unsigned short*)(cnt + NN);
    _Float16*       y    = (_Float16*)((char*)d_ws + (3 * NN * 4 + (size_t)NN * CAP * 2));

    k_init <<<NN / 256, 256, 0, stream>>>(deg);
    k_build<<<NN, 256, 0, stream>>>(A, deg, cnt, csr);
    k_dinv <<<NN / 256, 256, 0, stream>>>(deg, dinv);
    k_xform<<<(NB * NN) / XR, 256, 0, stream>>>(x, W, y);
    k_agg2 <<<dim3(NN / 4, NB / 4), 256, 0, stream>>>(y, cnt, csr, dinv, bias, out);
}

// Round 11
// 87.089 us; speedup vs baseline: 1.1882x; 1.1882x over previous
//
#include <hip/hip_runtime.h>

// GCN layer, transform-first pipeline:
//   k_init  : zero degree array
//   k_build : scan A once -> u16 CSR + column degrees (atomic +1.0, exact)
//   k_dinv  : dinv = rsqrt(1 + deg)
//   k_xform : y = x @ W^T in fp16 via MFMA 16x16x32 (fp32 accum), layout [b][n][o]
//   k_agg2  : out[b,n,:] = dinv[n]*(sum_m dinv[m]*y[b,m,:] + dinv[n]*y[b,n,:]) + bias
// k_agg2 = R5-proven body (56µs, per-(node,batch) wave, f16x8/lane, f32 accum)
// with XCD-PINNED batch mapping: xcd = bid&7 (HW round-robin), batch = 2*xcd +
// ((bid>>3)>>10) -> each XCD's L2 holds only its own <=2MB y-slice, cutting
// beyond-L2 replication (R5 FETCH 66MB ~= 4x y). R10's 4-batch fusion REVERTED:
// it halved concurrency (occ 72->34%) on an LLC-latency-bound gather.

#define NN 4096
#define FD 128
#define NB 16
#define CAP 96      // max neighbors/row (mean ~41, sd ~6.4; 96 = +8.6 sigma)
#define CPAD 100    // (CAP+1 self) padded to multiple of 4

typedef float     f32x2 __attribute__((ext_vector_type(2)));
typedef float     f32x4 __attribute__((ext_vector_type(4)));
typedef _Float16  f16x4 __attribute__((ext_vector_type(4)));
typedef _Float16  f16x8 __attribute__((ext_vector_type(8)));
typedef int       i32x2 __attribute__((ext_vector_type(2)));

__global__ __launch_bounds__(256) void k_init(float* __restrict__ deg) {
    deg[blockIdx.x * 256 + threadIdx.x] = 0.0f;
}

__global__ __launch_bounds__(256) void k_build(const float* __restrict__ A,
                                               float* __restrict__ deg,
                                               int* __restrict__ cnt,
                                               unsigned short* __restrict__ csr) {
    __shared__ int sCnt[256];
    const int n = blockIdx.x, t = threadIdx.x;
    const float* row = A + (size_t)n * NN + t * 16;
    float r[16];
    *(f32x4*)&r[0]  = ((const f32x4*)row)[0];
    *(f32x4*)&r[4]  = ((const f32x4*)row)[1];
    *(f32x4*)&r[8]  = ((const f32x4*)row)[2];
    *(f32x4*)&r[12] = ((const f32x4*)row)[3];

    int c = 0;
    #pragma unroll
    for (int j = 0; j < 16; ++j) c += (r[j] != 0.0f) ? 1 : 0;
    sCnt[t] = c;
    __syncthreads();
    for (int off = 1; off < 256; off <<= 1) {
        const int v = sCnt[t];
        const int u = (t >= off) ? sCnt[t - off] : 0;
        __syncthreads();
        sCnt[t] = v + u;
        __syncthreads();
    }
    int pos = sCnt[t] - c;                      // exclusive prefix (sorted order)
    #pragma unroll
    for (int j = 0; j < 16; ++j) {
        if (r[j] != 0.0f) {
            const int m = t * 16 + j;
            if (pos < CAP) csr[(size_t)n * CAP + pos] = (unsigned short)m;
            ++pos;
            atomicAdd(&deg[m], 1.0f);           // exact integer-valued fp adds
        }
    }
    if (t == 255) {
        int tot = sCnt[255];
        cnt[n] = tot < CAP ? tot : CAP;
    }
}

__global__ __launch_bounds__(256) void k_dinv(const float* __restrict__ deg,
                                              float* __restrict__ dinv) {
    const int i = blockIdx.x * 256 + threadIdx.x;
    dinv[i] = rsqrtf(1.0f + deg[i]);
}

// ---- MFMA transform: y[r][o] = sum_f x[r][f] * W[o][f], fp16 out ----
#define XR 128
#define XP 136
__global__ __launch_bounds__(256) void k_xform(const float* __restrict__ x,
                                               const float* __restrict__ W,
                                               _Float16* __restrict__ y) {
    __shared__ _Float16 sX[XR][XP];   // 34.8 KB
    __shared__ _Float16 sW[FD][XP];   // 34.8 KB
    const int t = threadIdx.x;
    const size_t rbase = (size_t)blockIdx.x * XR;

    #pragma unroll
    for (int i = 0; i < 8; ++i) {
        const int id = t + i * 256;
        const int o = id >> 4, f8 = (id & 15) * 8;
        const f32x4 a = *(const f32x4*)&W[(size_t)o * FD + f8];
        const f32x4 b = *(const f32x4*)&W[(size_t)o * FD + f8 + 4];
        f16x8 h;
        h[0]=(_Float16)a.x; h[1]=(_Float16)a.y; h[2]=(_Float16)a.z; h[3]=(_Float16)a.w;
        h[4]=(_Float16)b.x; h[5]=(_Float16)b.y; h[6]=(_Float16)b.z; h[7]=(_Float16)b.w;
        *(f16x8*)&sW[o][f8] = h;
    }
    #pragma unroll
    for (int i = 0; i < 8; ++i) {
        const int id = t + i * 256;
        const int r = id >> 4, f8 = (id & 15) * 8;
        const f32x4 a = *(const f32x4*)&x[(rbase + r) * FD + f8];
        const f32x4 b = *(const f32x4*)&x[(rbase + r) * FD + f8 + 4];
        f16x8 h;
        h[0]=(_Float16)a.x; h[1]=(_Float16)a.y; h[2]=(_Float16)a.z; h[3]=(_Float16)a.w;
        h[4]=(_Float16)b.x; h[5]=(_Float16)b.y; h[6]=(_Float16)b.z; h[7]=(_Float16)b.w;
        *(f16x8*)&sX[r][f8] = h;
    }
    __syncthreads();

    const int w = t >> 6, lane = t & 63;
    const int lrow = lane & 15, koct = (lane >> 4) * 8;
    f32x4 acc[2][8] = {};
    #pragma unroll
    for (int kc = 0; kc < 4; ++kc) {
        const int ko = kc * 32 + koct;
        f16x8 aa0 = *(const f16x8*)&sX[w * 32 + lrow][ko];
        f16x8 aa1 = *(const f16x8*)&sX[w * 32 + 16 + lrow][ko];
        #pragma unroll
        for (int nt = 0; nt < 8; ++nt) {
            const f16x8 bb = *(const f16x8*)&sW[nt * 16 + lrow][ko];
            acc[0][nt] = __builtin_amdgcn_mfma_f32_16x16x32_f16(aa0, bb, acc[0][nt], 0, 0, 0);
            acc[1][nt] = __builtin_amdgcn_mfma_f32_16x16x32_f16(aa1, bb, acc[1][nt], 0, 0, 0);
        }
    }
    // C layout (m89-verified): col = lane&15, row = (lane>>4)*4 + reg
    #pragma unroll
    for (int mt = 0; mt < 2; ++mt) {
        const size_t row0 = rbase + w * 32 + mt * 16 + (lane >> 4) * 4;
        #pragma unroll
        for (int nt = 0; nt < 8; ++nt) {
            const int col = nt * 16 + (lane & 15);
            #pragma unroll
            for (int r = 0; r < 4; ++r)
                y[(row0 + r) * FD + col] = (_Float16)acc[mt][nt][r];
        }
    }
}

// ---- aggregation: 1D grid of NN/4 * NB blocks, 256 thr (4 waves, 1 node each).
// XCD-pinned batches: xcd = bid&7 (HW round-robin), batch = 2*xcd + ((bid>>3)>>10),
// node-group = (bid>>3)&1023. lane: rq = lane>>4 (slot class), fo = (lane&15)*8.
__global__ __launch_bounds__(256) void k_agg2(const _Float16* __restrict__ y,
                                              const int* __restrict__ cnt,
                                              const unsigned short* __restrict__ csr,
                                              const float* __restrict__ dinv,
                                              const float* __restrict__ bias,
                                              float* __restrict__ out) {
    __shared__ int sL[4][CPAD * 2];              // (element-offset m*FD, f32 wt bits)
    const int t = threadIdx.x, w = t >> 6, lane = t & 63;
    const int bid = blockIdx.x;
    const int xcd = bid & 7;
    const int j   = bid >> 3;                    // 0..2047
    const int b   = 2 * xcd + (j >> 10);         // batches pinned to XCD
    const int ng  = j & 1023;
    const int n   = ng * 4 + w;
    const int c = cnt[n];
    const int totPad = (c + 1 + 3) & ~3;         // +self, pad to x4 (zero-weight)

    for (int k = lane; k < totPad; k += 64) {
        int m; float wv;
        if (k < c)       { m = csr[(size_t)n * CAP + k]; wv = dinv[m]; }
        else if (k == c) { m = n; wv = dinv[n]; }
        else             { m = n; wv = 0.0f; }
        sL[w][2 * k]     = m << 7;               // element offset (m * FD)
        sL[w][2 * k + 1] = __float_as_int(wv);
    }
    __syncthreads();

    const int rq = lane >> 4, fo = (lane & 15) * 8;
    const _Float16* yb = y + (size_t)b * (NN * FD) + fo;

    float acc[8] = {};
    i32x2 e = *(const i32x2*)&sL[w][2 * rq];
    f16x8 p = *(const f16x8*)(yb + e.x);
    float wt = __int_as_float(e.y);
    for (int k = rq + 4; k < totPad; k += 4) {
        const i32x2 e2 = *(const i32x2*)&sL[w][2 * k];
        const f16x8 p2 = *(const f16x8*)(yb + e2.x);
        const float wt2 = __int_as_float(e2.y);
        #pragma unroll
        for (int j2 = 0; j2 < 8; ++j2) acc[j2] = fmaf(wt, (float)p[j2], acc[j2]);
        p = p2; wt = wt2;
    }
    #pragma unroll
    for (int j2 = 0; j2 < 8; ++j2) acc[j2] = fmaf(wt, (float)p[j2], acc[j2]);

    // reduce the 4 slot-class partials across lanes (xor 16, then 32), in f32
    #pragma unroll
    for (int j2 = 0; j2 < 8; ++j2) {
        acc[j2] += __shfl_xor(acc[j2], 16);
        acc[j2] += __shfl_xor(acc[j2], 32);
    }

    if (lane < 32) {
        const float dn = dinv[n];
        const int h = lane >> 4;                 // low/high quad of my octet
        const int f0 = (lane & 15) * 8 + h * 4;
        const f32x4 bb = *(const f32x4*)(bias + f0);
        f32x4 o;
        o.x = acc[h * 4 + 0] * dn + bb.x;
        o.y = acc[h * 4 + 1] * dn + bb.y;
        o.z = acc[h * 4 + 2] * dn + bb.z;
        o.w = acc[h * 4 + 3] * dn + bb.w;
        f32x4* dst = (f32x4*)(out + ((size_t)b * NN + n) * FD + f0);
        __builtin_nontemporal_store(o, dst);
    }
}

extern "C" void kernel_launch(void* const* d_in, const int* in_sizes, int n_in,
                              void* d_out, int out_size, void* d_ws, size_t ws_size,
                              hipStream_t stream) {
    const float* A    = (const float*)d_in[0];   // (4096,4096)
    const float* x    = (const float*)d_in[1];   // (16,4096,128)
    const float* W    = (const float*)d_in[2];   // (128,128)
    const float* bias = (const float*)d_in[3];   // (128,)
    float* out = (float*)d_out;                  // (16,4096,128)

    // ws layout: deg 16K | dinv 16K | cnt 16K | csr 768K | y fp16 16M  (~17 MB)
    float*          deg  = (float*)d_ws;
    float*          dinv = deg + NN;
    int*            cnt  = (int*)(dinv + NN);
    unsigned short* csr  = (unsigned short*)(cnt + NN);
    _Float16*       y    = (_Float16*)((char*)d_ws + (3 * NN * 4 + (size_t)NN * CAP * 2));

    k_init <<<NN / 256, 256, 0, stream>>>(deg);
    k_build<<<NN, 256, 0, stream>>>(A, deg, cnt, csr);
    k_dinv <<<NN / 256, 256, 0, stream>>>(deg, dinv);
    k_xform<<<(NB * NN) / XR, 256, 0, stream>>>(x, W, y);
    k_agg2 <<<(NN / 4) * NB, 256, 0, stream>>>(y, cnt, csr, dinv, bias, out);
}

// Round 12
// 77.220 us; speedup vs baseline: 1.3401x; 1.1278x over previous
//
#include <hip/hip_runtime.h>

// GCN layer, transform-first pipeline:
//   memset  : zero degree array (hipMemsetAsync)
//   k_bx    : FAT kernel: blocks 0..511 = xform (y = x@W^T, fp16 MFMA);
//             blocks 512..4607 = build (A scan -> u16 CSR + degrees). Overlapped.
//   k_dinv  : dinv = rsqrt(1 + deg)
//   k_agg2  : out[b,n,:] = dinv[n]*(sum_m dinv[m]*y[b,m,:] + dinv[n]*y[b,n,:]) + bias
// k_agg2: R11 XCD-pinned structure, now 2-BATCH fused: wave owns (node, b0=2*xcd,
// b1=b0+1) — the pinned pair, so each XCD still only holds its 2MB y-slice.
// Two dwordx4 loads share one voffset -> 2x memory-level parallelism per wave,
// 16 fma_mix per ds_read_b64. f32 accum (pk-f16 NaN'd in R6/R7).

#define NN 4096
#define FD 128
#define NB 16
#define CAP 96      // max neighbors/row (mean ~41, sd ~6.4; 96 = +8.6 sigma)
#define CPAD 104    // (CAP+1 self) padded, all slots staged unconditionally
#define XB 512      // xform blocks in fat kernel

typedef float     f32x4 __attribute__((ext_vector_type(4)));
typedef _Float16  f16x8 __attribute__((ext_vector_type(8)));
typedef int       i32x2 __attribute__((ext_vector_type(2)));

#define XR 128
#define XP 136

// ---- fat kernel: xform (blocks 0..XB-1) | build (blocks XB..XB+NN-1) ----
__global__ __launch_bounds__(256) void k_bx(const float* __restrict__ A,
                                            float* __restrict__ deg,
                                            int* __restrict__ cnt,
                                            unsigned short* __restrict__ csr,
                                            const float* __restrict__ x,
                                            const float* __restrict__ W,
                                            _Float16* __restrict__ y) {
    __shared__ __align__(16) char smem[2 * XR * XP * 2];   // 69632 B (union)
    const int t = threadIdx.x;

    if (blockIdx.x < XB) {
        // ================= xform: y[r][o] = sum_f x[r][f]*W[o][f] =================
        _Float16 (*sX)[XP] = (_Float16(*)[XP])smem;
        _Float16 (*sW)[XP] = (_Float16(*)[XP])(smem + XR * XP * 2);
        const size_t rbase = (size_t)blockIdx.x * XR;

        #pragma unroll
        for (int i = 0; i < 8; ++i) {
            const int id = t + i * 256;
            const int o = id >> 4, f8 = (id & 15) * 8;
            const f32x4 a = *(const f32x4*)&W[(size_t)o * FD + f8];
            const f32x4 b = *(const f32x4*)&W[(size_t)o * FD + f8 + 4];
            f16x8 h;
            h[0]=(_Float16)a.x; h[1]=(_Float16)a.y; h[2]=(_Float16)a.z; h[3]=(_Float16)a.w;
            h[4]=(_Float16)b.x; h[5]=(_Float16)b.y; h[6]=(_Float16)b.z; h[7]=(_Float16)b.w;
            *(f16x8*)&sW[o][f8] = h;
        }
        #pragma unroll
        for (int i = 0; i < 8; ++i) {
            const int id = t + i * 256;
            const int r = id >> 4, f8 = (id & 15) * 8;
            const f32x4 a = *(const f32x4*)&x[(rbase + r) * FD + f8];
            const f32x4 b = *(const f32x4*)&x[(rbase + r) * FD + f8 + 4];
            f16x8 h;
            h[0]=(_Float16)a.x; h[1]=(_Float16)a.y; h[2]=(_Float16)a.z; h[3]=(_Float16)a.w;
            h[4]=(_Float16)b.x; h[5]=(_Float16)b.y; h[6]=(_Float16)b.z; h[7]=(_Float16)b.w;
            *(f16x8*)&sX[r][f8] = h;
        }
        __syncthreads();

        const int w = t >> 6, lane = t & 63;
        const int lrow = lane & 15, koct = (lane >> 4) * 8;
        f32x4 acc[2][8] = {};
        #pragma unroll
        for (int kc = 0; kc < 4; ++kc) {
            const int ko = kc * 32 + koct;
            f16x8 aa0 = *(const f16x8*)&sX[w * 32 + lrow][ko];
            f16x8 aa1 = *(const f16x8*)&sX[w * 32 + 16 + lrow][ko];
            #pragma unroll
            for (int nt = 0; nt < 8; ++nt) {
                const f16x8 bb = *(const f16x8*)&sW[nt * 16 + lrow][ko];
                acc[0][nt] = __builtin_amdgcn_mfma_f32_16x16x32_f16(aa0, bb, acc[0][nt], 0, 0, 0);
                acc[1][nt] = __builtin_amdgcn_mfma_f32_16x16x32_f16(aa1, bb, acc[1][nt], 0, 0, 0);
            }
        }
        // C layout (m89-verified): col = lane&15, row = (lane>>4)*4 + reg
        #pragma unroll
        for (int mt = 0; mt < 2; ++mt) {
            const size_t row0 = rbase + w * 32 + mt * 16 + (lane >> 4) * 4;
            #pragma unroll
            for (int nt = 0; nt < 8; ++nt) {
                const int col = nt * 16 + (lane & 15);
                #pragma unroll
                for (int r = 0; r < 4; ++r)
                    y[(row0 + r) * FD + col] = (_Float16)acc[mt][nt][r];
            }
        }
        return;
    }

    // ================= build: row scan -> CSR + degrees =================
    int* sCnt = (int*)smem;
    const int n = blockIdx.x - XB;
    const float* row = A + (size_t)n * NN + t * 16;
    float r[16];
    *(f32x4*)&r[0]  = ((const f32x4*)row)[0];
    *(f32x4*)&r[4]  = ((const f32x4*)row)[1];
    *(f32x4*)&r[8]  = ((const f32x4*)row)[2];
    *(f32x4*)&r[12] = ((const f32x4*)row)[3];

    int c = 0;
    #pragma unroll
    for (int j = 0; j < 16; ++j) c += (r[j] != 0.0f) ? 1 : 0;
    sCnt[t] = c;
    __syncthreads();
    for (int off = 1; off < 256; off <<= 1) {
        const int v = sCnt[t];
        const int u = (t >= off) ? sCnt[t - off] : 0;
        __syncthreads();
        sCnt[t] = v + u;
        __syncthreads();
    }
    int pos = sCnt[t] - c;                      // exclusive prefix (sorted order)
    #pragma unroll
    for (int j = 0; j < 16; ++j) {
        if (r[j] != 0.0f) {
            const int m = t * 16 + j;
            if (pos < CAP) csr[(size_t)n * CAP + pos] = (unsigned short)m;
            ++pos;
            atomicAdd(&deg[m], 1.0f);           // exact integer-valued fp adds
        }
    }
    if (t == 255) {
        int tot = sCnt[255];
        cnt[n] = tot < CAP ? tot : CAP;
    }
}

__global__ __launch_bounds__(256) void k_dinv(const float* __restrict__ deg,
                                              float* __restrict__ dinv) {
    const int i = blockIdx.x * 256 + threadIdx.x;
    dinv[i] = rsqrtf(1.0f + deg[i]);
}

// ---- aggregation: 1D grid of (NN/4)*(NB/2) blocks, 256 thr (4 waves, 1 node each).
// XCD-pinned batch PAIR: xcd = bid&7, b0 = 2*xcd, b1 = b0+1; node-group = bid>>3.
// lane: rq = lane>>4 (slot class), fo = (lane&15)*16 bytes (feature octet).
__global__ __launch_bounds__(256) void k_agg2(const _Float16* __restrict__ y,
                                              const int* __restrict__ cnt,
                                              const unsigned short* __restrict__ csr,
                                              const float* __restrict__ dinv,
                                              const float* __restrict__ bias,
                                              float* __restrict__ out) {
    __shared__ int sL[4][CPAD * 2];              // (byte-offset m*256, f32 wt bits)
    const int t = threadIdx.x, w = t >> 6, lane = t & 63;
    const int bid = blockIdx.x;
    const int xcd = bid & 7;
    const int b0  = 2 * xcd;                     // pinned batch pair
    const int n   = (bid >> 3) * 4 + w;
    const int c = cnt[n];
    const int totPad = (c + 1 + 3) & ~3;         // +self, pad to x4 (zero-weight)

    // stage EVERY slot (pads zero-weight self) — no read can hit unstaged LDS
    for (int k = lane; k < CPAD; k += 64) {
        int m; float wv;
        if (k < c)       { m = csr[(size_t)n * CAP + k]; wv = dinv[m]; }
        else if (k == c) { m = n; wv = dinv[n]; }
        else             { m = n; wv = 0.0f; }
        sL[w][2 * k]     = m << 8;               // byte offset (m * FD * 2)
        sL[w][2 * k + 1] = __float_as_int(wv);
    }
    __syncthreads();

    const int rq = lane >> 4;
    const int fo = (lane & 15) * 16;             // byte offset of feature octet
    const char* yb0 = (const char*)y + (size_t)b0 * (NN * FD * 2);
    const char* yb1 = yb0 + (size_t)(NN * FD * 2);

    float acc0[8] = {}, acc1[8] = {};
    i32x2 e = *(const i32x2*)&sL[w][2 * rq];
    int voff = e.x + fo;
    f16x8 pA = *(const f16x8*)(yb0 + (size_t)(unsigned)voff);
    f16x8 pB = *(const f16x8*)(yb1 + (size_t)(unsigned)voff);
    float wt = __int_as_float(e.y);
    for (int k = rq + 4; k < totPad; k += 4) {
        const i32x2 e2 = *(const i32x2*)&sL[w][2 * k];
        const int v2 = e2.x + fo;
        const f16x8 nA = *(const f16x8*)(yb0 + (size_t)(unsigned)v2);
        const f16x8 nB = *(const f16x8*)(yb1 + (size_t)(unsigned)v2);
        const float wt2 = __int_as_float(e2.y);
        #pragma unroll
        for (int j = 0; j < 8; ++j) {
            acc0[j] = fmaf(wt, (float)pA[j], acc0[j]);
            acc1[j] = fmaf(wt, (float)pB[j], acc1[j]);
        }
        pA = nA; pB = nB; wt = wt2;
    }
    #pragma unroll
    for (int j = 0; j < 8; ++j) {
        acc0[j] = fmaf(wt, (float)pA[j], acc0[j]);
        acc1[j] = fmaf(wt, (float)pB[j], acc1[j]);
    }

    // reduce the 4 slot-class partials across lanes (xor 16, then 32), in f32
    #pragma unroll
    for (int j = 0; j < 8; ++j) {
        acc0[j] += __shfl_xor(acc0[j], 16);
        acc0[j] += __shfl_xor(acc0[j], 32);
        acc1[j] += __shfl_xor(acc1[j], 16);
        acc1[j] += __shfl_xor(acc1[j], 32);
    }

    if (lane < 32) {
        const float dn = dinv[n];
        const int h = lane >> 4;                 // low/high quad of my octet
        const int f0 = (lane & 15) * 8 + h * 4;
        const f32x4 bb = *(const f32x4*)(bias + f0);
        f32x4 o0, o1;
        o0.x = acc0[h * 4 + 0] * dn + bb.x;
        o0.y = acc0[h * 4 + 1] * dn + bb.y;
        o0.z = acc0[h * 4 + 2] * dn + bb.z;
        o0.w = acc0[h * 4 + 3] * dn + bb.w;
        o1.x = acc1[h * 4 + 0] * dn + bb.x;
        o1.y = acc1[h * 4 + 1] * dn + bb.y;
        o1.z = acc1[h * 4 + 2] * dn + bb.z;
        o1.w = acc1[h * 4 + 3] * dn + bb.w;
        f32x4* d0 = (f32x4*)(out + ((size_t)b0 * NN + n) * FD + f0);
        f32x4* d1 = (f32x4*)(out + ((size_t)(b0 + 1) * NN + n) * FD + f0);
        __builtin_nontemporal_store(o0, d0);
        __builtin_nontemporal_store(o1, d1);
    }
}

extern "C" void kernel_launch(void* const* d_in, const int* in_sizes, int n_in,
                              void* d_out, int out_size, void* d_ws, size_t ws_size,
                              hipStream_t stream) {
    const float* A    = (const float*)d_in[0];   // (4096,4096)
    const float* x    = (const float*)d_in[1];   // (16,4096,128)
    const float* W    = (const float*)d_in[2];   // (128,128)
    const float* bias = (const float*)d_in[3];   // (128,)
    float* out = (float*)d_out;                  // (16,4096,128)

    // ws layout: deg 16K | dinv 16K | cnt 16K | csr 768K | y fp16 16M  (~17 MB)
    float*          deg  = (float*)d_ws;
    float*          dinv = deg + NN;
    int*            cnt  = (int*)(dinv + NN);
    unsigned short* csr  = (unsigned short*)(cnt + NN);
    _Float16*       y    = (_Float16*)((char*)d_ws + (3 * NN * 4 + (size_t)NN * CAP * 2));

    hipMemsetAsync(deg, 0, NN * sizeof(float), stream);
    k_bx  <<<XB + NN, 256, 0, stream>>>(A, deg, cnt, csr, x, W, y);
    k_dinv<<<NN / 256, 256, 0, stream>>>(deg, dinv);
    k_agg2<<<(NN / 4) * (NB / 2), 256, 0, stream>>>(y, cnt, csr, dinv, bias, out);
}

// Round 13
// 75.964 us; speedup vs baseline: 1.3622x; 1.0165x over previous
//
#include <hip/hip_runtime.h>

// GCN layer, transform-first pipeline:
//   memset  : zero degree array (hipMemsetAsync)
//   k_bx    : FAT kernel v2: blocks 0..511 = xform (y = x@W^T, fp16 MFMA, A-frags
//             loaded DIRECT from global, only W in LDS = 34.8KB -> 4 blocks/CU);
//             blocks 512..4607 = build (A scan -> u16 CSR + degrees, 16 waves/CU).
//   k_dinv  : dinv = rsqrt(1 + deg)
//   k_agg2  : out = dinv[n]*(sum dinv[m]*y[b,m,:] + dinv[n]*y[b,n,:]) + bias
// k_agg2: XCD-pinned batch pair (R11/R12), 2-batch fused, now 2-DEEP slot
// prefetch: 4 dwordx4 in flight per lane. f32 accum (pk-f16 NaN'd R6/R7).

#define NN 4096
#define FD 128
#define NB 16
#define CAP 96      // max neighbors/row (mean ~41, sd ~6.4; 96 = +8.6 sigma)
#define CPAD 104    // (CAP+1 self) padded to x8, all slots staged unconditionally
#define XB 512      // xform blocks in fat kernel

typedef float     f32x4 __attribute__((ext_vector_type(4)));
typedef _Float16  f16x8 __attribute__((ext_vector_type(8)));
typedef int       i32x2 __attribute__((ext_vector_type(2)));

#define XP 136      // padded f16 row for sW

// ---- fat kernel v2: xform (blocks 0..XB-1) | build (blocks XB..XB+NN-1) ----
__global__ __launch_bounds__(256) void k_bx(const float* __restrict__ A,
                                            float* __restrict__ deg,
                                            int* __restrict__ cnt,
                                            unsigned short* __restrict__ csr,
                                            const float* __restrict__ x,
                                            const float* __restrict__ W,
                                            _Float16* __restrict__ y) {
    __shared__ __align__(16) char smem[FD * XP * 2];   // 34816 B (union)
    const int t = threadIdx.x;

    if (blockIdx.x < XB) {
        // ======== xform: y[r][o] = sum_f x[r][f]*W[o][f], A-frags from global ========
        _Float16 (*sW)[XP] = (_Float16(*)[XP])smem;
        const size_t rbase = (size_t)blockIdx.x * 128;

        #pragma unroll
        for (int i = 0; i < 8; ++i) {            // stage W (f32 -> f16) in LDS
            const int id = t + i * 256;
            const int o = id >> 4, f8 = (id & 15) * 8;
            const f32x4 a = *(const f32x4*)&W[(size_t)o * FD + f8];
            const f32x4 b = *(const f32x4*)&W[(size_t)o * FD + f8 + 4];
            f16x8 h;
            h[0]=(_Float16)a.x; h[1]=(_Float16)a.y; h[2]=(_Float16)a.z; h[3]=(_Float16)a.w;
            h[4]=(_Float16)b.x; h[5]=(_Float16)b.y; h[6]=(_Float16)b.z; h[7]=(_Float16)b.w;
            *(f16x8*)&sW[o][f8] = h;
        }
        __syncthreads();

        const int w = t >> 6, lane = t & 63;
        const int lrow = lane & 15, koct = (lane >> 4) * 8;
        const float* xr0 = x + (rbase + w * 32 + lrow) * FD;        // m-tile 0 row
        const float* xr1 = xr0 + 16 * FD;                           // m-tile 1 row
        f32x4 acc[2][8] = {};
        #pragma unroll
        for (int kc = 0; kc < 4; ++kc) {
            const int ko = kc * 32 + koct;
            const f32x4 a0 = *(const f32x4*)&xr0[ko];
            const f32x4 a1 = *(const f32x4*)&xr0[ko + 4];
            const f32x4 b0 = *(const f32x4*)&xr1[ko];
            const f32x4 b1 = *(const f32x4*)&xr1[ko + 4];
            f16x8 aa0, aa1;
            aa0[0]=(_Float16)a0.x; aa0[1]=(_Float16)a0.y; aa0[2]=(_Float16)a0.z; aa0[3]=(_Float16)a0.w;
            aa0[4]=(_Float16)a1.x; aa0[5]=(_Float16)a1.y; aa0[6]=(_Float16)a1.z; aa0[7]=(_Float16)a1.w;
            aa1[0]=(_Float16)b0.x; aa1[1]=(_Float16)b0.y; aa1[2]=(_Float16)b0.z; aa1[3]=(_Float16)b0.w;
            aa1[4]=(_Float16)b1.x; aa1[5]=(_Float16)b1.y; aa1[6]=(_Float16)b1.z; aa1[7]=(_Float16)b1.w;
            #pragma unroll
            for (int nt = 0; nt < 8; ++nt) {
                const f16x8 bb = *(const f16x8*)&sW[nt * 16 + lrow][ko];
                acc[0][nt] = __builtin_amdgcn_mfma_f32_16x16x32_f16(aa0, bb, acc[0][nt], 0, 0, 0);
                acc[1][nt] = __builtin_amdgcn_mfma_f32_16x16x32_f16(aa1, bb, acc[1][nt], 0, 0, 0);
            }
        }
        // C layout (m89-verified): col = lane&15, row = (lane>>4)*4 + reg
        #pragma unroll
        for (int mt = 0; mt < 2; ++mt) {
            const size_t row0 = rbase + w * 32 + mt * 16 + (lane >> 4) * 4;
            #pragma unroll
            for (int nt = 0; nt < 8; ++nt) {
                const int col = nt * 16 + (lane & 15);
                #pragma unroll
                for (int r = 0; r < 4; ++r)
                    y[(row0 + r) * FD + col] = (_Float16)acc[mt][nt][r];
            }
        }
        return;
    }

    // ================= build: row scan -> CSR + degrees =================
    int* sCnt = (int*)smem;
    const int n = blockIdx.x - XB;
    const float* row = A + (size_t)n * NN + t * 16;
    float r[16];
    *(f32x4*)&r[0]  = ((const f32x4*)row)[0];
    *(f32x4*)&r[4]  = ((const f32x4*)row)[1];
    *(f32x4*)&r[8]  = ((const f32x4*)row)[2];
    *(f32x4*)&r[12] = ((const f32x4*)row)[3];

    int c = 0;
    #pragma unroll
    for (int j = 0; j < 16; ++j) c += (r[j] != 0.0f) ? 1 : 0;
    sCnt[t] = c;
    __syncthreads();
    for (int off = 1; off < 256; off <<= 1) {
        const int v = sCnt[t];
        const int u = (t >= off) ? sCnt[t - off] : 0;
        __syncthreads();
        sCnt[t] = v + u;
        __syncthreads();
    }
    int pos = sCnt[t] - c;                      // exclusive prefix (sorted order)
    #pragma unroll
    for (int j = 0; j < 16; ++j) {
        if (r[j] != 0.0f) {
            const int m = t * 16 + j;
            if (pos < CAP) csr[(size_t)n * CAP + pos] = (unsigned short)m;
            ++pos;
            atomicAdd(&deg[m], 1.0f);           // exact integer-valued fp adds
        }
    }
    if (t == 255) {
        int tot = sCnt[255];
        cnt[n] = tot < CAP ? tot : CAP;
    }
}

__global__ __launch_bounds__(256) void k_dinv(const float* __restrict__ deg,
                                              float* __restrict__ dinv) {
    const int i = blockIdx.x * 256 + threadIdx.x;
    dinv[i] = rsqrtf(1.0f + deg[i]);
}

// ---- aggregation: 1D grid (NN/4)*(NB/2) blocks, 256 thr (4 waves, 1 node each).
// XCD-pinned batch PAIR: xcd = bid&7, b0 = 2*xcd; node-group = bid>>3.
// lane: rq = lane>>4 (slot class), fo = (lane&15)*16 B. 2-deep slot prefetch.
__global__ __launch_bounds__(256) void k_agg2(const _Float16* __restrict__ y,
                                              const int* __restrict__ cnt,
                                              const unsigned short* __restrict__ csr,
                                              const float* __restrict__ dinv,
                                              const float* __restrict__ bias,
                                              float* __restrict__ out) {
    __shared__ int sL[4][CPAD * 2];              // (byte-offset m*256, f32 wt bits)
    const int t = threadIdx.x, w = t >> 6, lane = t & 63;
    const int bid = blockIdx.x;
    const int xcd = bid & 7;
    const int b0  = 2 * xcd;                     // pinned batch pair
    const int n   = (bid >> 3) * 4 + w;
    const int c = cnt[n];
    const int totPad = (c + 1 + 7) & ~7;         // +self, pad to x8 (<= CPAD)

    // stage EVERY slot (pads zero-weight self) — no read can hit unstaged LDS
    for (int k = lane; k < CPAD; k += 64) {
        int m; float wv;
        if (k < c)       { m = csr[(size_t)n * CAP + k]; wv = dinv[m]; }
        else if (k == c) { m = n; wv = dinv[n]; }
        else             { m = n; wv = 0.0f; }
        sL[w][2 * k]     = m << 8;               // byte offset (m * FD * 2)
        sL[w][2 * k + 1] = __float_as_int(wv);
    }
    __syncthreads();

    const int rq = lane >> 4;
    const int fo = (lane & 15) * 16;             // byte offset of feature octet
    const char* yb0 = (const char*)y + (size_t)b0 * (NN * FD * 2);
    const char* yb1 = yb0 + (size_t)(NN * FD * 2);

    float acc0[8] = {}, acc1[8] = {};
    i32x2 e0 = *(const i32x2*)&sL[w][2 * rq];
    i32x2 e1 = *(const i32x2*)&sL[w][2 * (rq + 4)];
    unsigned v0 = (unsigned)(e0.x + fo), v1 = (unsigned)(e1.x + fo);
    f16x8 pA0 = *(const f16x8*)(yb0 + v0);
    f16x8 pB0 = *(const f16x8*)(yb1 + v0);
    f16x8 pA1 = *(const f16x8*)(yb0 + v1);
    f16x8 pB1 = *(const f16x8*)(yb1 + v1);
    float wt0 = __int_as_float(e0.y), wt1 = __int_as_float(e1.y);

    for (int k = 8; k < totPad; k += 8) {
        const i32x2 f0 = *(const i32x2*)&sL[w][2 * (k + rq)];
        const i32x2 f1 = *(const i32x2*)&sL[w][2 * (k + rq + 4)];
        const unsigned u0 = (unsigned)(f0.x + fo), u1 = (unsigned)(f1.x + fo);
        const f16x8 nA0 = *(const f16x8*)(yb0 + u0);
        const f16x8 nB0 = *(const f16x8*)(yb1 + u0);
        const f16x8 nA1 = *(const f16x8*)(yb0 + u1);
        const f16x8 nB1 = *(const f16x8*)(yb1 + u1);
        #pragma unroll
        for (int j = 0; j < 8; ++j) {
            acc0[j] = fmaf(wt0, (float)pA0[j], acc0[j]);
            acc1[j] = fmaf(wt0, (float)pB0[j], acc1[j]);
            acc0[j] = fmaf(wt1, (float)pA1[j], acc0[j]);
            acc1[j] = fmaf(wt1, (float)pB1[j], acc1[j]);
        }
        pA0 = nA0; pB0 = nB0; pA1 = nA1; pB1 = nB1;
        wt0 = __int_as_float(f0.y); wt1 = __int_as_float(f1.y);
    }
    #pragma unroll
    for (int j = 0; j < 8; ++j) {
        acc0[j] = fmaf(wt0, (float)pA0[j], acc0[j]);
        acc1[j] = fmaf(wt0, (float)pB0[j], acc1[j]);
        acc0[j] = fmaf(wt1, (float)pA1[j], acc0[j]);
        acc1[j] = fmaf(wt1, (float)pB1[j], acc1[j]);
    }

    // reduce the 4 slot-class partials across lanes (xor 16, then 32), in f32
    #pragma unroll
    for (int j = 0; j < 8; ++j) {
        acc0[j] += __shfl_xor(acc0[j], 16);
        acc0[j] += __shfl_xor(acc0[j], 32);
        acc1[j] += __shfl_xor(acc1[j], 16);
        acc1[j] += __shfl_xor(acc1[j], 32);
    }

    if (lane < 32) {
        const float dn = dinv[n];
        const int h = lane >> 4;                 // low/high quad of my octet
        const int f0 = (lane & 15) * 8 + h * 4;
        const f32x4 bb = *(const f32x4*)(bias + f0);
        f32x4 o0, o1;
        o0.x = acc0[h * 4 + 0] * dn + bb.x;
        o0.y = acc0[h * 4 + 1] * dn + bb.y;
        o0.z = acc0[h * 4 + 2] * dn + bb.z;
        o0.w = acc0[h * 4 + 3] * dn + bb.w;
        o1.x = acc1[h * 4 + 0] * dn + bb.x;
        o1.y = acc1[h * 4 + 1] * dn + bb.y;
        o1.z = acc1[h * 4 + 2] * dn + bb.z;
        o1.w = acc1[h * 4 + 3] * dn + bb.w;
        f32x4* d0 = (f32x4*)(out + ((size_t)b0 * NN + n) * FD + f0);
        f32x4* d1 = (f32x4*)(out + ((size_t)(b0 + 1) * NN + n) * FD + f0);
        __builtin_nontemporal_store(o0, d0);
        __builtin_nontemporal_store(o1, d1);
    }
}

extern "C" void kernel_launch(void* const* d_in, const int* in_sizes, int n_in,
                              void* d_out, int out_size, void* d_ws, size_t ws_size,
                              hipStream_t stream) {
    const float* A    = (const float*)d_in[0];   // (4096,4096)
    const float* x    = (const float*)d_in[1];   // (16,4096,128)
    const float* W    = (const float*)d_in[2];   // (128,128)
    const float* bias = (const float*)d_in[3];   // (128,)
    float* out = (float*)d_out;                  // (16,4096,128)

    // ws layout: deg 16K | dinv 16K | cnt 16K | csr 768K | y fp16 16M  (~17 MB)
    float*          deg  = (float*)d_ws;
    float*          dinv = deg + NN;
    int*            cnt  = (int*)(dinv + NN);
    unsigned short* csr  = (unsigned short*)(cnt + NN);
    _Float16*       y    = (_Float16*)((char*)d_ws + (3 * NN * 4 + (size_t)NN * CAP * 2));

    hipMemsetAsync(deg, 0, NN * sizeof(float), stream);
    k_bx  <<<XB + NN, 256, 0, stream>>>(A, deg, cnt, csr, x, W, y);
    k_dinv<<<NN / 256, 256, 0, stream>>>(deg, dinv);
    k_agg2<<<(NN / 4) * (NB / 2), 256, 0, stream>>>(y, cnt, csr, dinv, bias, out);
}

// Round 15
// 75.924 us; speedup vs baseline: 1.3629x; 1.0005x over previous
//
#include <hip/hip_runtime.h>

// GCN layer, transform-first pipeline:
//   memset  : zero degree array (hipMemsetAsync)
//   k_bx    : FAT kernel: blocks 0..511 = xform (y = x@W^T, fp16 MFMA, A=W/B=x
//             operand order -> C[o][r] fragment -> coalesced f16x4 stores);
//             blocks 512..4607 = build (A scan -> u16 CSR + degrees).
//   k_agg2  : out = dinv[n]*(sum dinv[m]*y[b,m,:] + dinv[n]*y[b,n,:]) + bias,
//             dinv computed inline as rsqrtf(1+deg) (k_dinv kernel removed).
// k_agg2 = R12-exact 1-deep loop (R13's 2-deep prefetch regressed: occ 65->43%).
// XCD-pinned batch pair: xcd = bid&7, b0 = 2*xcd. f32 accum (pk-f16 NaN'd R6/R7).
// [R14 resubmit: container unresponsive, no data]

#define NN 4096
#define FD 128
#define NB 16
#define CAP 96      // max neighbors/row (mean ~41, sd ~6.4; 96 = +8.6 sigma)
#define CPAD 104    // (CAP+1 self) padded, all slots staged unconditionally
#define XB 512      // xform blocks in fat kernel

typedef float     f32x4 __attribute__((ext_vector_type(4)));
typedef _Float16  f16x4 __attribute__((ext_vector_type(4)));
typedef _Float16  f16x8 __attribute__((ext_vector_type(8)));
typedef int       i32x2 __attribute__((ext_vector_type(2)));

#define XP 136      // padded f16 row for sW

// ---- fat kernel: xform (blocks 0..XB-1) | build (blocks XB..XB+NN-1) ----
__global__ __launch_bounds__(256) void k_bx(const float* __restrict__ A,
                                            float* __restrict__ deg,
                                            int* __restrict__ cnt,
                                            unsigned short* __restrict__ csr,
                                            const float* __restrict__ x,
                                            const float* __restrict__ W,
                                            _Float16* __restrict__ y) {
    __shared__ __align__(16) char smem[FD * XP * 2];   // 34816 B (union)
    const int t = threadIdx.x;

    if (blockIdx.x < XB) {
        // ==== xform: y[r][o] = sum_f x[r][f]*W[o][f]; MFMA A=W, B=x ====
        _Float16 (*sW)[XP] = (_Float16(*)[XP])smem;
        const size_t rbase = (size_t)blockIdx.x * 128;

        #pragma unroll
        for (int i = 0; i < 8; ++i) {            // stage W (f32 -> f16) in LDS
            const int id = t + i * 256;
            const int o = id >> 4, f8 = (id & 15) * 8;
            const f32x4 a = *(const f32x4*)&W[(size_t)o * FD + f8];
            const f32x4 b = *(const f32x4*)&W[(size_t)o * FD + f8 + 4];
            f16x8 h;
            h[0]=(_Float16)a.x; h[1]=(_Float16)a.y; h[2]=(_Float16)a.z; h[3]=(_Float16)a.w;
            h[4]=(_Float16)b.x; h[5]=(_Float16)b.y; h[6]=(_Float16)b.z; h[7]=(_Float16)b.w;
            *(f16x8*)&sW[o][f8] = h;
        }
        __syncthreads();

        const int w = t >> 6, lane = t & 63;
        const int lrow = lane & 15, koct = (lane >> 4) * 8;
        const float* xr0 = x + (rbase + w * 32 + lrow) * FD;        // r-tile 0 row
        const float* xr1 = xr0 + 16 * FD;                           // r-tile 1 row
        f32x4 acc[2][8] = {};                    // [r-tile][o-tile]
        #pragma unroll
        for (int kc = 0; kc < 4; ++kc) {
            const int ko = kc * 32 + koct;
            const f32x4 a0 = *(const f32x4*)&xr0[ko];
            const f32x4 a1 = *(const f32x4*)&xr0[ko + 4];
            const f32x4 b0 = *(const f32x4*)&xr1[ko];
            const f32x4 b1 = *(const f32x4*)&xr1[ko + 4];
            f16x8 xx0, xx1;                      // B-fragments (x rows)
            xx0[0]=(_Float16)a0.x; xx0[1]=(_Float16)a0.y; xx0[2]=(_Float16)a0.z; xx0[3]=(_Float16)a0.w;
            xx0[4]=(_Float16)a1.x; xx0[5]=(_Float16)a1.y; xx0[6]=(_Float16)a1.z; xx0[7]=(_Float16)a1.w;
            xx1[0]=(_Float16)b0.x; xx1[1]=(_Float16)b0.y; xx1[2]=(_Float16)b0.z; xx1[3]=(_Float16)b0.w;
            xx1[4]=(_Float16)b1.x; xx1[5]=(_Float16)b1.y; xx1[6]=(_Float16)b1.z; xx1[7]=(_Float16)b1.w;
            #pragma unroll
            for (int ot = 0; ot < 8; ++ot) {
                const f16x8 ww = *(const f16x8*)&sW[ot * 16 + lrow][ko];  // A-fragment
                acc[0][ot] = __builtin_amdgcn_mfma_f32_16x16x32_f16(ww, xx0, acc[0][ot], 0, 0, 0);
                acc[1][ot] = __builtin_amdgcn_mfma_f32_16x16x32_f16(ww, xx1, acc[1][ot], 0, 0, 0);
            }
        }
        // C layout (swapped): o = ot*16 + (lane>>4)*4 + reg, r = rt*16 + (lane&15)
        // -> 4 consecutive o per lane = one f16x4 (8B) store
        #pragma unroll
        for (int rt = 0; rt < 2; ++rt) {
            const size_t row = rbase + w * 32 + rt * 16 + (lane & 15);
            #pragma unroll
            for (int ot = 0; ot < 8; ++ot) {
                f16x4 h;
                h[0] = (_Float16)acc[rt][ot][0];
                h[1] = (_Float16)acc[rt][ot][1];
                h[2] = (_Float16)acc[rt][ot][2];
                h[3] = (_Float16)acc[rt][ot][3];
                *(f16x4*)&y[row * FD + ot * 16 + (lane >> 4) * 4] = h;
            }
        }
        return;
    }

    // ================= build: row scan -> CSR + degrees =================
    int* sCnt = (int*)smem;
    const int n = blockIdx.x - XB;
    const float* row = A + (size_t)n * NN + t * 16;
    float r[16];
    *(f32x4*)&r[0]  = ((const f32x4*)row)[0];
    *(f32x4*)&r[4]  = ((const f32x4*)row)[1];
    *(f32x4*)&r[8]  = ((const f32x4*)row)[2];
    *(f32x4*)&r[12] = ((const f32x4*)row)[3];

    int c = 0;
    #pragma unroll
    for (int j = 0; j < 16; ++j) c += (r[j] != 0.0f) ? 1 : 0;
    sCnt[t] = c;
    __syncthreads();
    for (int off = 1; off < 256; off <<= 1) {
        const int v = sCnt[t];
        const int u = (t >= off) ? sCnt[t - off] : 0;
        __syncthreads();
        sCnt[t] = v + u;
        __syncthreads();
    }
    int pos = sCnt[t] - c;                      // exclusive prefix (sorted order)
    #pragma unroll
    for (int j = 0; j < 16; ++j) {
        if (r[j] != 0.0f) {
            const int m = t * 16 + j;
            if (pos < CAP) csr[(size_t)n * CAP + pos] = (unsigned short)m;
            ++pos;
            atomicAdd(&deg[m], 1.0f);           // exact integer-valued fp adds
        }
    }
    if (t == 255) {
        int tot = sCnt[255];
        cnt[n] = tot < CAP ? tot : CAP;
    }
}

// ---- aggregation: 1D grid (NN/4)*(NB/2) blocks, 256 thr (4 waves, 1 node each).
// XCD-pinned batch PAIR: xcd = bid&7, b0 = 2*xcd; node-group = bid>>3.
// lane: rq = lane>>4 (slot class), fo = (lane&15)*16 B. R12-exact 1-deep loop.
__global__ __launch_bounds__(256) void k_agg2(const _Float16* __restrict__ y,
                                              const int* __restrict__ cnt,
                                              const unsigned short* __restrict__ csr,
                                              const float* __restrict__ deg,
                                              const float* __restrict__ bias,
                                              float* __restrict__ out) {
    __shared__ int sL[4][CPAD * 2];              // (byte-offset m*256, f32 wt bits)
    const int t = threadIdx.x, w = t >> 6, lane = t & 63;
    const int bid = blockIdx.x;
    const int xcd = bid & 7;
    const int b0  = 2 * xcd;                     // pinned batch pair
    const int n   = (bid >> 3) * 4 + w;
    const int c = cnt[n];
    const int totPad = (c + 1 + 3) & ~3;         // +self, pad to x4 (zero-weight)

    // stage EVERY slot (pads zero-weight self); dinv computed inline (rsqrt)
    for (int k = lane; k < CPAD; k += 64) {
        int m; float wv;
        if (k < c)       { m = csr[(size_t)n * CAP + k]; wv = rsqrtf(1.0f + deg[m]); }
        else if (k == c) { m = n; wv = rsqrtf(1.0f + deg[n]); }
        else             { m = n; wv = 0.0f; }
        sL[w][2 * k]     = m << 8;               // byte offset (m * FD * 2)
        sL[w][2 * k + 1] = __float_as_int(wv);
    }
    __syncthreads();

    const int rq = lane >> 4;
    const int fo = (lane & 15) * 16;             // byte offset of feature octet
    const char* yb0 = (const char*)y + (size_t)b0 * (NN * FD * 2);
    const char* yb1 = yb0 + (size_t)(NN * FD * 2);

    float acc0[8] = {}, acc1[8] = {};
    i32x2 e = *(const i32x2*)&sL[w][2 * rq];
    unsigned voff = (unsigned)(e.x + fo);
    f16x8 pA = *(const f16x8*)(yb0 + voff);
    f16x8 pB = *(const f16x8*)(yb1 + voff);
    float wt = __int_as_float(e.y);
    for (int k = rq + 4; k < totPad; k += 4) {
        const i32x2 e2 = *(const i32x2*)&sL[w][2 * k];
        const unsigned v2 = (unsigned)(e2.x + fo);
        const f16x8 nA = *(const f16x8*)(yb0 + v2);
        const f16x8 nB = *(const f16x8*)(yb1 + v2);
        const float wt2 = __int_as_float(e2.y);
        #pragma unroll
        for (int j = 0; j < 8; ++j) {
            acc0[j] = fmaf(wt, (float)pA[j], acc0[j]);
            acc1[j] = fmaf(wt, (float)pB[j], acc1[j]);
        }
        pA = nA; pB = nB; wt = wt2;
    }
    #pragma unroll
    for (int j = 0; j < 8; ++j) {
        acc0[j] = fmaf(wt, (float)pA[j], acc0[j]);
        acc1[j] = fmaf(wt, (float)pB[j], acc1[j]);
    }

    // reduce the 4 slot-class partials across lanes (xor 16, then 32), in f32
    #pragma unroll
    for (int j = 0; j < 8; ++j) {
        acc0[j] += __shfl_xor(acc0[j], 16);
        acc0[j] += __shfl_xor(acc0[j], 32);
        acc1[j] += __shfl_xor(acc1[j], 16);
        acc1[j] += __shfl_xor(acc1[j], 32);
    }

    if (lane < 32) {
        const float dn = rsqrtf(1.0f + deg[n]);
        const int h = lane >> 4;                 // low/high quad of my octet
        const int f0 = (lane & 15) * 8 + h * 4;
        const f32x4 bb = *(const f32x4*)(bias + f0);
        f32x4 o0, o1;
        o0.x = acc0[h * 4 + 0] * dn + bb.x;
        o0.y = acc0[h * 4 + 1] * dn + bb.y;
        o0.z = acc0[h * 4 + 2] * dn + bb.z;
        o0.w = acc0[h * 4 + 3] * dn + bb.w;
        o1.x = acc1[h * 4 + 0] * dn + bb.x;
        o1.y = acc1[h * 4 + 1] * dn + bb.y;
        o1.z = acc1[h * 4 + 2] * dn + bb.z;
        o1.w = acc1[h * 4 + 3] * dn + bb.w;
        f32x4* d0 = (f32x4*)(out + ((size_t)b0 * NN + n) * FD + f0);
        f32x4* d1 = (f32x4*)(out + ((size_t)(b0 + 1) * NN + n) * FD + f0);
        __builtin_nontemporal_store(o0, d0);
        __builtin_nontemporal_store(o1, d1);
    }
}

extern "C" void kernel_launch(void* const* d_in, const int* in_sizes, int n_in,
                              void* d_out, int out_size, void* d_ws, size_t ws_size,
                              hipStream_t stream) {
    const float* A    = (const float*)d_in[0];   // (4096,4096)
    const float* x    = (const float*)d_in[1];   // (16,4096,128)
    const float* W    = (const float*)d_in[2];   // (128,128)
    const float* bias = (const float*)d_in[3];   // (128,)
    float* out = (float*)d_out;                  // (16,4096,128)

    // ws layout: deg 16K | (unused 16K) | cnt 16K | csr 768K | y fp16 16M
    float*          deg  = (float*)d_ws;
    int*            cnt  = (int*)((char*)d_ws + 2 * NN * 4);
    unsigned short* csr  = (unsigned short*)(cnt + NN);
    _Float16*       y    = (_Float16*)((char*)d_ws + (3 * NN * 4 + (size_t)NN * CAP * 2));

    hipMemsetAsync(deg, 0, NN * sizeof(float), stream);
    k_bx  <<<XB + NN, 256, 0, stream>>>(A, deg, cnt, csr, x, W, y);
    k_agg2<<<(NN / 4) * (NB / 2), 256, 0, stream>>>(y, cnt, csr, deg, bias, out);
}